// Round 10
// baseline (81.924 us; speedup 1.0000x reference)
//
#include <hip/hip_runtime.h>
#include <math.h>

#define BATCH   262144
#define CLUSTER 100

typedef float nt_f4 __attribute__((ext_vector_type(4)));  // clang-native vec4

// Analytic Lorentz boost matrix B = I - (g*mag)*nK + (g-1)*nK^2:
//   B[0][0]     = g
//   B[0][j+1]   = B[j+1][0] = -(g*mag)*n_j
//   B[i+1][j+1] = delta_ij + (g-1)*n_i*n_j
__device__ inline void boost_mat(float bx, float by, float bz, float B[4][4]) {
    float m2  = bx * bx + by * by + bz * bz;
    float mag = sqrtf(m2);
    float nx = bx / mag, ny = by / mag, nz = bz / mag;
    float g  = 1.0f / sqrtf(1.0f - mag * mag);
    float gm = g * mag;
    float gm1 = g - 1.0f;
    float n[3] = {nx, ny, nz};
    B[0][0] = 1.0f + gm1 * (nx * nx + ny * ny + nz * nz);
    for (int j = 0; j < 3; ++j) {
        B[0][j + 1] = -gm * n[j];
        B[j + 1][0] = -gm * n[j];
    }
    for (int i = 0; i < 3; ++i)
        for (int j = 0; j < 3; ++j)
            B[i + 1][j + 1] = ((i == j) ? 1.0f : 0.0f) + gm1 * n[i] * n[j];
}

#define DOT4(mm, vv) ((mm).x*(vv).x + (mm).y*(vv).y + (mm).z*(vv).z + (mm).w*(vv).w)
#define DOTV(mm, vv) ((mm).x*(vv)[0] + (mm).y*(vv)[1] + (mm).z*(vv)[2] + (mm).w*(vv)[3])

// out[b][a] = sum_c sum_d M[c][a][d] * T[b][c][d],  M_c = BiM @ (W_c * BoM_c)
// EXACT R2 structure (best measured: 77.9 us) with ONE change: T loads use
// __builtin_nontemporal_load (nt bit) -- T is a 419MB read-once stream; nt
// skips L2 allocation so the stream doesn't churn the 32MB L2.
// 8-lane group: lane q handles clusters c = 8t+q -> full 128B line per row per
// load instruction. Each group owns rows (base+g, base+g+8): 16 rows per wave.
__global__ __launch_bounds__(256) void lorentz_fused_kernel(
        const float* __restrict__ T,
        const float* __restrict__ Bo,
        const float* __restrict__ Bi,
        const float* __restrict__ W,
        float* __restrict__ out) {
    __shared__ float sM[CLUSTER * 16];

    int tid = threadIdx.x;
    // Build all 100 M_c matrices in-block.
    if (tid < CLUSTER) {
        float BiM[4][4], BoM[4][4];
        boost_mat(Bi[0], Bi[1], Bi[2], BiM);
        boost_mat(Bo[tid * 3 + 0], Bo[tid * 3 + 1], Bo[tid * 3 + 2], BoM);
        float w = W[tid];
        for (int a = 0; a < 4; ++a)
            for (int d = 0; d < 4; ++d) {
                float s = 0.0f;
                for (int e = 0; e < 4; ++e)
                    s += BiM[a][e] * (w * BoM[e][d]);
                sM[tid * 16 + a * 4 + d] = s;
            }
    }
    __syncthreads();

    int wave = tid >> 6;
    int lane = tid & 63;
    int q = lane & 7;       // position in 8-lane group
    int g = lane >> 3;      // group 0..7
    long long base = (long long)blockIdx.x * 64 + wave * 16;
    long long row0 = base + g;
    long long row1 = base + g + 8;

    const nt_f4* P0 = (const nt_f4*)(T + row0 * (CLUSTER * 4));
    const nt_f4* P1 = (const nt_f4*)(T + row1 * (CLUSTER * 4));

    float4 a0 = {0.f, 0.f, 0.f, 0.f};
    float4 a1 = a0;

    #pragma unroll 4
    for (int t = 0; t < 12; ++t) {
        int c = 8 * t + q;
        nt_f4 v0 = __builtin_nontemporal_load(P0 + c);
        nt_f4 v1 = __builtin_nontemporal_load(P1 + c);
        const float4* m = (const float4*)(sM + c * 16);
        float4 m0 = m[0], m1 = m[1], m2 = m[2], m3 = m[3];
        a0.x += DOTV(m0, v0); a0.y += DOTV(m1, v0); a0.z += DOTV(m2, v0); a0.w += DOTV(m3, v0);
        a1.x += DOTV(m0, v1); a1.y += DOTV(m1, v1); a1.z += DOTV(m2, v1); a1.w += DOTV(m3, v1);
    }
    // tail: c = 96..99 handled by lanes q<4
    if (q < 4) {
        int c = 96 + q;
        nt_f4 v0 = __builtin_nontemporal_load(P0 + c);
        nt_f4 v1 = __builtin_nontemporal_load(P1 + c);
        const float4* m = (const float4*)(sM + c * 16);
        float4 m0 = m[0], m1 = m[1], m2 = m[2], m3 = m[3];
        a0.x += DOTV(m0, v0); a0.y += DOTV(m1, v0); a0.z += DOTV(m2, v0); a0.w += DOTV(m3, v0);
        a1.x += DOTV(m0, v1); a1.y += DOTV(m1, v1); a1.z += DOTV(m2, v1); a1.w += DOTV(m3, v1);
    }

    // butterfly reduce across the 8-lane group; all lanes end with full sums
    #define RED(f) f += __shfl_xor(f, 1); f += __shfl_xor(f, 2); f += __shfl_xor(f, 4);
    RED(a0.x) RED(a0.y) RED(a0.z) RED(a0.w)
    RED(a1.x) RED(a1.y) RED(a1.z) RED(a1.w)
    #undef RED

    // wave writes 16 consecutive rows (256B contiguous)
    if (q == 0) ((float4*)out)[row0] = a0;
    if (q == 1) ((float4*)out)[row1] = a1;
}

extern "C" void kernel_launch(void* const* d_in, const int* in_sizes, int n_in,
                              void* d_out, int out_size, void* d_ws, size_t ws_size,
                              hipStream_t stream) {
    const float* T  = (const float*)d_in[0];
    const float* Bo = (const float*)d_in[1];
    const float* Bi = (const float*)d_in[2];
    const float* W  = (const float*)d_in[3];
    // d_in[4] = K_mats (folded into analytic boost formula)

    float* out = (float*)d_out;

    int blocks = BATCH / 64;   // 64 rows per block (4 waves x 16 rows)
    lorentz_fused_kernel<<<blocks, 256, 0, stream>>>(T, Bo, Bi, W, out);
}

// Round 11
// 77.705 us; speedup vs baseline: 1.0543x; 1.0543x over previous
//
#include <hip/hip_runtime.h>
#include <math.h>

#define BATCH   262144
#define CLUSTER 100

// Analytic Lorentz boost matrix B = I - (g*mag)*nK + (g-1)*nK^2:
//   B[0][0]     = g
//   B[0][j+1]   = B[j+1][0] = -(g*mag)*n_j
//   B[i+1][j+1] = delta_ij + (g-1)*n_i*n_j
__device__ inline void boost_mat(float bx, float by, float bz, float B[4][4]) {
    float m2  = bx * bx + by * by + bz * bz;
    float mag = sqrtf(m2);
    float nx = bx / mag, ny = by / mag, nz = bz / mag;
    float g  = 1.0f / sqrtf(1.0f - mag * mag);
    float gm = g * mag;
    float gm1 = g - 1.0f;
    float n[3] = {nx, ny, nz};
    B[0][0] = 1.0f + gm1 * (nx * nx + ny * ny + nz * nz);
    for (int j = 0; j < 3; ++j) {
        B[0][j + 1] = -gm * n[j];
        B[j + 1][0] = -gm * n[j];
    }
    for (int i = 0; i < 3; ++i)
        for (int j = 0; j < 3; ++j)
            B[i + 1][j + 1] = ((i == j) ? 1.0f : 0.0f) + gm1 * n[i] * n[j];
}

#define DOT4(mm, vv) ((mm).x*(vv).x + (mm).y*(vv).y + (mm).z*(vv).z + (mm).w*(vv).w)

// out[b][a] = sum_c sum_d M[c][a][d] * T[b][c][d],  M_c = BiM @ (W_c * BoM_c)
// Best-measured structure (R2, 77.9 us = 86% of the 6.29 TB/s copy ceiling):
// 8-lane group: lane q handles clusters c = 8t+q -> full 128B line per row per
// load instruction, 8 line-segments per VMEM instr (row stride 1600B).
// Each group owns rows (base+g, base+g+8): 16 rows per wave. M built in-block.
// Knobs tested and refuted: 64/256/512B segments, LDS staging, multi-tile,
// nontemporal loads, reg-capped deep unroll (see session ledger R1-R9).
__global__ __launch_bounds__(256) void lorentz_fused_kernel(
        const float* __restrict__ T,
        const float* __restrict__ Bo,
        const float* __restrict__ Bi,
        const float* __restrict__ W,
        float* __restrict__ out) {
    __shared__ float sM[CLUSTER * 16];

    int tid = threadIdx.x;
    // Build all 100 M_c matrices in-block.
    if (tid < CLUSTER) {
        float BiM[4][4], BoM[4][4];
        boost_mat(Bi[0], Bi[1], Bi[2], BiM);
        boost_mat(Bo[tid * 3 + 0], Bo[tid * 3 + 1], Bo[tid * 3 + 2], BoM);
        float w = W[tid];
        for (int a = 0; a < 4; ++a)
            for (int d = 0; d < 4; ++d) {
                float s = 0.0f;
                for (int e = 0; e < 4; ++e)
                    s += BiM[a][e] * (w * BoM[e][d]);
                sM[tid * 16 + a * 4 + d] = s;
            }
    }
    __syncthreads();

    int wave = tid >> 6;
    int lane = tid & 63;
    int q = lane & 7;       // position in 8-lane group
    int g = lane >> 3;      // group 0..7
    long long base = (long long)blockIdx.x * 64 + wave * 16;
    long long row0 = base + g;
    long long row1 = base + g + 8;

    const float* P0 = T + row0 * (CLUSTER * 4);
    const float* P1 = T + row1 * (CLUSTER * 4);

    float4 a0 = {0.f, 0.f, 0.f, 0.f};
    float4 a1 = a0;

    #pragma unroll 4
    for (int t = 0; t < 12; ++t) {
        int c = 8 * t + q;
        float4 v0 = *(const float4*)(P0 + c * 4);
        float4 v1 = *(const float4*)(P1 + c * 4);
        const float4* m = (const float4*)(sM + c * 16);
        float4 m0 = m[0], m1 = m[1], m2 = m[2], m3 = m[3];
        a0.x += DOT4(m0, v0); a0.y += DOT4(m1, v0); a0.z += DOT4(m2, v0); a0.w += DOT4(m3, v0);
        a1.x += DOT4(m0, v1); a1.y += DOT4(m1, v1); a1.z += DOT4(m2, v1); a1.w += DOT4(m3, v1);
    }
    // tail: c = 96..99 handled by lanes q<4
    if (q < 4) {
        int c = 96 + q;
        float4 v0 = *(const float4*)(P0 + c * 4);
        float4 v1 = *(const float4*)(P1 + c * 4);
        const float4* m = (const float4*)(sM + c * 16);
        float4 m0 = m[0], m1 = m[1], m2 = m[2], m3 = m[3];
        a0.x += DOT4(m0, v0); a0.y += DOT4(m1, v0); a0.z += DOT4(m2, v0); a0.w += DOT4(m3, v0);
        a1.x += DOT4(m0, v1); a1.y += DOT4(m1, v1); a1.z += DOT4(m2, v1); a1.w += DOT4(m3, v1);
    }

    // butterfly reduce across the 8-lane group; all lanes end with full sums
    #define RED(f) f += __shfl_xor(f, 1); f += __shfl_xor(f, 2); f += __shfl_xor(f, 4);
    RED(a0.x) RED(a0.y) RED(a0.z) RED(a0.w)
    RED(a1.x) RED(a1.y) RED(a1.z) RED(a1.w)
    #undef RED

    // wave writes 16 consecutive rows (256B contiguous)
    if (q == 0) ((float4*)out)[row0] = a0;
    if (q == 1) ((float4*)out)[row1] = a1;
}

extern "C" void kernel_launch(void* const* d_in, const int* in_sizes, int n_in,
                              void* d_out, int out_size, void* d_ws, size_t ws_size,
                              hipStream_t stream) {
    const float* T  = (const float*)d_in[0];
    const float* Bo = (const float*)d_in[1];
    const float* Bi = (const float*)d_in[2];
    const float* W  = (const float*)d_in[3];
    // d_in[4] = K_mats (folded into analytic boost formula)

    float* out = (float*)d_out;

    int blocks = BATCH / 64;   // 64 rows per block (4 waves x 16 rows)
    lorentz_fused_kernel<<<blocks, 256, 0, stream>>>(T, Bo, Bi, W, out);
}